// Round 13
// baseline (387.095 us; speedup 1.0000x reference)
//
#include <hip/hip_runtime.h>
#include <hip/hip_fp16.h>
#include <math.h>

#define NN 25000
#define NE 400000
#define HID 64
#define F_IN 256
#define N_CLASS 32
#define MAXL 4          // x_all stores up to 4 layer slices
#define KVS 3           // K/V layer slots
#define WPAD 264        // f16 row stride of W^T in LDS (256 + 8 pad -> 4-bank rotate)
#define SCAN_NB 98      // ceil(NN/256)

typedef _Float16 f16;
typedef _Float16 f16x2 __attribute__((ext_vector_type(2)));
typedef _Float16 f16x8 __attribute__((ext_vector_type(8)));
typedef float f32x4 __attribute__((ext_vector_type(4)));

union F16x8 {
    f16x8 v;
    f16x2 h[4];
    __half2 hh[4];
};

__device__ __forceinline__ float dot2(f16x2 a, f16x2 b, float c) {
#if __has_builtin(__builtin_amdgcn_fdot2)
    return __builtin_amdgcn_fdot2(a, b, c, false);
#else
    return c + (float)a[0] * (float)b[0] + (float)a[1] * (float)b[1];
#endif
}

// ---------- prep: W1 fp16 transpose || zero deg || zero dhist (one grid) ----------
__global__ void prep_kernel(const float* __restrict__ w, f16* __restrict__ wt,
                            int* __restrict__ deg, int* __restrict__ dhist, int n) {
    int b = blockIdx.x, t = threadIdx.x;
    if (b < 64) {                       // wprep: 16384 elements
        int e = b * 256 + t;
        int k = e >> 6, nn = e & 63;
        wt[nn * F_IN + k] = (f16)w[e];
    } else if (b < 64 + SCAN_NB) {      // zero deg
        int i = (b - 64) * 256 + t;
        if (i < n) deg[i] = 0;
    } else {                            // zero dhist (256 buckets)
        dhist[t] = 0;
    }
}

// ---------- fused: deg histogram (blocks < degBlocks)  ||  lin1 MFMA ----------
__global__ void __launch_bounds__(256) deg_lin1_kernel(
        const int* __restrict__ col, int* __restrict__ deg, int E, int degBlocks,
        const float* __restrict__ x, const f16x8* __restrict__ wt,
        const float* __restrict__ b, float* __restrict__ x_all, int n) {
    __shared__ f16 wlds[64 * WPAD];
    if (blockIdx.x < degBlocks) {
        int e = blockIdx.x * 256 + threadIdx.x;
        if (e < E) atomicAdd(&deg[col[e]], 1);
        return;
    }
    int bid = blockIdx.x - degBlocks;
    int t = threadIdx.x;
    #pragma unroll
    for (int j = 0; j < 8; ++j) {                 // stage all 2048 f16x8 units (32 KB)
        int idx = t + j * 256;
        int e = idx * 8;
        int nr = e >> 8, k0 = e & 255;
        *(f16x8*)&wlds[nr * WPAD + k0] = wt[idx];
    }
    __syncthreads();
    int wave = t >> 6, lane = t & 63;
    int m = lane & 15, quad = lane >> 4;
    int rowA = bid * 64 + wave * 16 + m;
    int rA = min(rowA, n - 1);                    // clamp; masked at store
    const float* xp = x + (size_t)rA * F_IN + quad * 8;
    f32x4 acc[4] = {};
    for (int kk = 0; kk < F_IN; kk += 32) {
        float4 x0 = *(const float4*)(xp + kk);
        float4 x1 = *(const float4*)(xp + kk + 4);
        f16x8 a;
        a[0] = (f16)x0.x; a[1] = (f16)x0.y; a[2] = (f16)x0.z; a[3] = (f16)x0.w;
        a[4] = (f16)x1.x; a[5] = (f16)x1.y; a[6] = (f16)x1.z; a[7] = (f16)x1.w;
        #pragma unroll
        for (int nt = 0; nt < 4; ++nt) {
            f16x8 bf = *(const f16x8*)&wlds[(nt * 16 + m) * WPAD + kk + quad * 8];
            acc[nt] = __builtin_amdgcn_mfma_f32_16x16x32_f16(a, bf, acc[nt], 0, 0, 0);
        }
    }
    int rowC = bid * 64 + wave * 16 + quad * 4;
    #pragma unroll
    for (int nt = 0; nt < 4; ++nt) {
        int c2 = nt * 16 + m;
        float bias = b[c2];
        #pragma unroll
        for (int r = 0; r < 4; ++r) {
            int row = rowC + r;
            if (row < n)
                x_all[(size_t)row * (MAXL * HID) + c2] = fmaxf(acc[nt][r] + bias, 0.f);
        }
    }
}

// ---------- scanA: per-block sums for rowptr scan + degree histogram ----------
__global__ void scanA_kernel(const int* __restrict__ deg, int* __restrict__ bsum,
                             int* __restrict__ dhist, int n) {
    __shared__ int lh[256];
    int t = threadIdx.x;
    lh[t] = 0;
    __syncthreads();
    int i = blockIdx.x * 256 + t;
    int v = (i < n) ? deg[i] : 0;
    if (i < n) atomicAdd(&lh[255 - min(v, 255)], 1);   // bucket 255-d: descending order
    #pragma unroll
    for (int off = 1; off < 64; off <<= 1) v += __shfl_xor(v, off);
    __shared__ int wsum[4];
    if ((t & 63) == 0) wsum[t >> 6] = v;
    __syncthreads();
    if (t == 0) bsum[blockIdx.x] = wsum[0] + wsum[1] + wsum[2] + wsum[3];
    if (lh[t]) atomicAdd(&dhist[t], lh[t]);
}

// ---------- bucketScan: exclusive scan of 256 degree buckets -> cursor ----------
__global__ void bucketScan_kernel(const int* __restrict__ dhist, int* __restrict__ bcur) {
    __shared__ int s[256];
    int t = threadIdx.x;
    int v = dhist[t];
    s[t] = v;
    __syncthreads();
    for (int off = 1; off < 256; off <<= 1) {
        int u = (t >= off) ? s[t - off] : 0;
        __syncthreads();
        s[t] += u;
        __syncthreads();
    }
    bcur[t] = s[t] - v;   // exclusive
}

// scanC: each block re-scans the (<=128) block sums in LDS, then local scan
__global__ void scanC_kernel(const int* __restrict__ deg, const int* __restrict__ bsum,
                             int* __restrict__ rowptr, int* __restrict__ cursor,
                             float* __restrict__ dis, int n) {
    __shared__ int s[128];
    int t = threadIdx.x;
    {   // inclusive HS scan of block sums
        int v = (t < SCAN_NB) ? bsum[t] : 0;
        s[t] = v;
        __syncthreads();
        for (int off = 1; off < 128; off <<= 1) {
            int u = (t >= off) ? s[t - off] : 0;
            __syncthreads();
            s[t] += u;
            __syncthreads();
        }
    }
    int base = (blockIdx.x > 0) ? s[blockIdx.x - 1] : 0;   // exclusive base of this block
    __syncthreads();

    int i = blockIdx.x * 256 + t;
    int lane = t & 63, w = t >> 6;
    int v = (i < n) ? deg[i] : 0;
    int x = v;   // inclusive wave scan
    #pragma unroll
    for (int off = 1; off < 64; off <<= 1) {
        int u = __shfl_up(x, off);
        if (lane >= off) x += u;
    }
    __shared__ int wsum[4];
    if (lane == 63) wsum[w] = x;
    __syncthreads();
    for (int ww = 0; ww < w; ++ww) base += wsum[ww];
    if (i < n) {
        int excl = base + x - v;
        rowptr[i] = excl;
        cursor[i] = excl;
        dis[i] = rsqrtf((float)(v + 1));   // +1 self loop
    }
}

// ---------- fused: scatter CSR || layer-1 transform (V only) + perm scatter ----------
__global__ void scatter_t1_kernel(const int* __restrict__ row, const int* __restrict__ col,
                                  int* __restrict__ cursor, int* __restrict__ csr_src,
                                  int E, int scatBlocks,
                                  const float* __restrict__ x_all,
                                  const float* __restrict__ wv, const float* __restrict__ bv,
                                  const float* __restrict__ dis,
                                  f16x2* __restrict__ KV,
                                  const int* __restrict__ deg, int* __restrict__ bcur,
                                  int* __restrict__ perm, int n) {
    if (blockIdx.x < scatBlocks) {
        int e = blockIdx.x * 256 + threadIdx.x;
        if (e >= E) return;
        int c = col[e];
        int p = atomicAdd(&cursor[c], 1);
        csr_src[p] = row[e];
        return;
    }
    int t = (blockIdx.x - scatBlocks) * 256 + threadIdx.x;
    int node = t >> 5, u = t & 31;
    if (node >= n) return;
    if (u == 0) {   // degree-sorted permutation (descending)
        int bb = 255 - min(deg[node], 255);
        int p = atomicAdd(&bcur[bb], 1);
        perm[p] = node;
    }
    int g = u >> 2;
    int o0 = (u & 3) * 2;
    const float4* xg4 = (const float4*)(x_all + (size_t)node * (MAXL * HID) + g * 8);
    float4 xa = xg4[0], xb = xg4[1];
    float xv[8] = {xa.x, xa.y, xa.z, xa.w, xb.x, xb.y, xb.z, xb.w};
    float d = dis[node];
    const float* wgv = wv + g * 64;
    float v0 = bv[g * 8 + o0], v1 = bv[g * 8 + o0 + 1];
    #pragma unroll
    for (int i = 0; i < 8; ++i) {
        v0 = fmaf(xv[i], wgv[i * 8 + o0], v0);
        v1 = fmaf(xv[i], wgv[i * 8 + o0 + 1], v1);
    }
    f16x2 vh; vh[0] = (f16)(v0 * d); vh[1] = (f16)(v1 * d);
    KV[((size_t)node * KVS * 2 + 1) * 32 + u] = vh;   // slice 0, V slot
}

// ---------- layer-1 gather: pure weighted V sum (softmax == 1) ----------
__global__ void gather1_kernel(const int* __restrict__ perm,
                               const int* __restrict__ rowptr, const int* __restrict__ deg,
                               const int* __restrict__ csr_src, const float* __restrict__ dis,
                               const f16x8* __restrict__ KV8, float* __restrict__ x_all, int n) {
    int wave = (int)((blockIdx.x * (size_t)blockDim.x + threadIdx.x) >> 6);
    int lane = threadIdx.x & 63;
    if (wave >= n) return;
    int c = perm[wave];
    int u = lane & 7;
    int slot = lane >> 3;
    float nc = dis[c];
    int beg = rowptr[c];
    int dc = deg[c] + 1;      // + self loop (virtual edge 0)
    float acc[8];
    #pragma unroll
    for (int i = 0; i < 8; ++i) acc[i] = 0.f;

    for (int j = 0; j < dc; j += 32) {
        int jj0 = j + slot, jj1 = jj0 + 8, jj2 = jj0 + 16, jj3 = jj0 + 24;
        bool va0 = jj0 < dc, va1 = jj1 < dc, va2 = jj2 < dc, va3 = jj3 < dc;
        int r0 = c, r1 = c, r2 = c, r3 = c;
        if (va0 && jj0 > 0) r0 = csr_src[beg + jj0 - 1];
        if (va1)            r1 = csr_src[beg + jj1 - 1];
        if (va2)            r2 = csr_src[beg + jj2 - 1];
        if (va3)            r3 = csr_src[beg + jj3 - 1];
        F16x8 v0, v1, v2, v3;
        v0.v = KV8[(size_t)r0 * (KVS * 2 * 8) + 8 + u];
        v1.v = KV8[(size_t)r1 * (KVS * 2 * 8) + 8 + u];
        v2.v = KV8[(size_t)r2 * (KVS * 2 * 8) + 8 + u];
        v3.v = KV8[(size_t)r3 * (KVS * 2 * 8) + 8 + u];
        __half2 p0 = __float2half2_rn(va0 ? 1.f : 0.f);
        __half2 p1 = __float2half2_rn(va1 ? 1.f : 0.f);
        __half2 p2 = __float2half2_rn(va2 ? 1.f : 0.f);
        __half2 p3 = __float2half2_rn(va3 ? 1.f : 0.f);
        __half2 ha[4];
        #pragma unroll
        for (int i2 = 0; i2 < 4; ++i2) {
            ha[i2] = __hmul2(p0, v0.hh[i2]);
            ha[i2] = __hfma2(p1, v1.hh[i2], ha[i2]);
            ha[i2] = __hfma2(p2, v2.hh[i2], ha[i2]);
            ha[i2] = __hfma2(p3, v3.hh[i2], ha[i2]);
        }
        #pragma unroll
        for (int i2 = 0; i2 < 4; ++i2) {
            float2 f = __half22float2(ha[i2]);
            acc[i2 * 2]     += f.x;
            acc[i2 * 2 + 1] += f.y;
        }
    }
    #pragma unroll
    for (int off = 8; off < 64; off <<= 1) {
        #pragma unroll
        for (int i = 0; i < 8; ++i) acc[i] += __shfl_xor(acc[i], off);
    }
    if (slot == 0) {
        float4* dst = (float4*)(x_all + ((size_t)c * MAXL + 1) * HID + u * 8);
        dst[0] = make_float4(fmaxf(acc[0] * nc, 0.f), fmaxf(acc[1] * nc, 0.f),
                             fmaxf(acc[2] * nc, 0.f), fmaxf(acc[3] * nc, 0.f));
        dst[1] = make_float4(fmaxf(acc[4] * nc, 0.f), fmaxf(acc[5] * nc, 0.f),
                             fmaxf(acc[6] * nc, 0.f), fmaxf(acc[7] * nc, 0.f));
    }
}

// ---------- per-node q/k/v grouped-linear transform (layers 2,3) ----------
// V is pre-scaled by dis[node]
__global__ void transform_kernel(const float* __restrict__ x_all,
                                 const float* __restrict__ wq, const float* __restrict__ bq,
                                 const float* __restrict__ wk, const float* __restrict__ bk,
                                 const float* __restrict__ wv, const float* __restrict__ bv,
                                 const float* __restrict__ dis,
                                 f16x2* __restrict__ Q2, f16x2* __restrict__ KV,
                                 int n, int L) {
    int t = blockIdx.x * blockDim.x + threadIdx.x;
    int node = t >> 5, u = t & 31;
    if (node >= n) return;
    int g = u >> 2;               // head/group of both dims
    int o0 = (u & 3) * 2;         // within-group output index of dim 2u
    const float* xrow = x_all + (size_t)node * (MAXL * HID);
    float d = dis[node];

    {   // Q from layer L-1
        const float4* xg4 = (const float4*)(xrow + (L - 1) * HID + g * 8);
        float4 xa = xg4[0], xb = xg4[1];
        float xv[8] = {xa.x, xa.y, xa.z, xa.w, xb.x, xb.y, xb.z, xb.w};
        const float* wg = wq + g * 64;
        float a0 = bq[g * 8 + o0], a1 = bq[g * 8 + o0 + 1];
        #pragma unroll
        for (int i = 0; i < 8; ++i) {
            a0 = fmaf(xv[i], wg[i * 8 + o0], a0);
            a1 = fmaf(xv[i], wg[i * 8 + o0 + 1], a1);
        }
        f16x2 q; q[0] = (f16)a0; q[1] = (f16)a1;
        Q2[(size_t)node * 32 + u] = q;
    }
    for (int ll = 0; ll < L; ++ll) {
        const float4* xg4 = (const float4*)(xrow + ll * HID + g * 8);
        float4 xa = xg4[0], xb = xg4[1];
        float xv[8] = {xa.x, xa.y, xa.z, xa.w, xb.x, xb.y, xb.z, xb.w};
        const float* wgk = wk + g * 64;
        const float* wgv = wv + g * 64;
        float k0 = bk[g * 8 + o0], k1 = bk[g * 8 + o0 + 1];
        float v0 = bv[g * 8 + o0], v1 = bv[g * 8 + o0 + 1];
        #pragma unroll
        for (int i = 0; i < 8; ++i) {
            k0 = fmaf(xv[i], wgk[i * 8 + o0], k0);
            k1 = fmaf(xv[i], wgk[i * 8 + o0 + 1], k1);
            v0 = fmaf(xv[i], wgv[i * 8 + o0], v0);
            v1 = fmaf(xv[i], wgv[i * 8 + o0 + 1], v1);
        }
        f16x2 kh; kh[0] = (f16)k0; kh[1] = (f16)k1;
        f16x2 vh; vh[0] = (f16)(v0 * d); vh[1] = (f16)(v1 * d);   // dis-scaled V
        size_t base = ((size_t)node * KVS + ll) * 2;
        KV[(base + 0) * 32 + u] = kh;
        KV[(base + 1) * 32 + u] = vh;
    }
}

// ---------- gather + attend core (layers 2,3): 32 edges/iter, straight-line ----------
// FINAL=true (L=3): fused classifier + log_softmax, writes `out`, skips x_all store.
template <int L, bool FINAL>
__global__ void gather_kernel(const int* __restrict__ perm,
                              const int* __restrict__ rowptr, const int* __restrict__ deg,
                              const int* __restrict__ csr_src, const float* __restrict__ dis,
                              const f16x8* __restrict__ Q8, const f16x8* __restrict__ KV8,
                              float* __restrict__ x_all,
                              const float* __restrict__ w2, const float* __restrict__ b2,
                              float* __restrict__ out, int n) {
    int wave = (int)((blockIdx.x * (size_t)blockDim.x + threadIdx.x) >> 6);
    int lane = threadIdx.x & 63;
    if (wave >= n) return;
    int c = perm[wave];
    int u = lane & 7;         // head
    int slot = lane >> 3;     // edge slot
    F16x8 q; q.v = Q8[(size_t)c * 8 + u];
    float nc = dis[c];
    int beg = rowptr[c];
    int dc = deg[c] + 1;      // + self loop (virtual edge 0)
    float acc[8];
    #pragma unroll
    for (int i = 0; i < 8; ++i) acc[i] = 0.f;

    for (int j = 0; j < dc; j += 32) {
        int jj0 = j + slot;
        int jj1 = jj0 + 8;
        int jj2 = jj0 + 16;
        int jj3 = jj0 + 24;
        bool va0 = jj0 < dc, va1 = jj1 < dc, va2 = jj2 < dc, va3 = jj3 < dc;
        int r0 = c, r1 = c, r2 = c, r3 = c;
        if (va0 && jj0 > 0) r0 = csr_src[beg + jj0 - 1];
        if (va1)            r1 = csr_src[beg + jj1 - 1];
        if (va2)            r2 = csr_src[beg + jj2 - 1];
        if (va3)            r3 = csr_src[beg + jj3 - 1];

        size_t rb0 = (size_t)r0 * (KVS * 2 * 8);
        size_t rb1 = (size_t)r1 * (KVS * 2 * 8);
        size_t rb2 = (size_t)r2 * (KVS * 2 * 8);
        size_t rb3 = (size_t)r3 * (KVS * 2 * 8);
        F16x8 kk0[L], vv0[L], kk1[L], vv1[L], kk2[L], vv2[L], kk3[L], vv3[L];
        #pragma unroll
        for (int ll = 0; ll < L; ++ll) {
            kk0[ll].v = KV8[rb0 + ll * 16 + u];
            vv0[ll].v = KV8[rb0 + ll * 16 + 8 + u];
            kk1[ll].v = KV8[rb1 + ll * 16 + u];
            vv1[ll].v = KV8[rb1 + ll * 16 + 8 + u];
            kk2[ll].v = KV8[rb2 + ll * 16 + u];
            vv2[ll].v = KV8[rb2 + ll * 16 + 8 + u];
            kk3[ll].v = KV8[rb3 + ll * 16 + u];
            vv3[ll].v = KV8[rb3 + ll * 16 + 8 + u];
        }

        // ---- pair A: edges 0,1 ----
        {
            float s0[L], s1[L];
            #pragma unroll
            for (int ll = 0; ll < L; ++ll) {
                float p0 = 0.f, p1 = 0.f;
                #pragma unroll
                for (int i2 = 0; i2 < 4; ++i2) {
                    p0 = dot2(q.h[i2], kk0[ll].h[i2], p0);
                    p1 = dot2(q.h[i2], kk1[ll].h[i2], p1);
                }
                s0[ll] = p0 * 0.35355339059327373f;   // 1/sqrt(8)
                s1[ll] = p1 * 0.35355339059327373f;
            }
            float m0 = s0[0], m1 = s1[0];
            #pragma unroll
            for (int ll = 1; ll < L; ++ll) { m0 = fmaxf(m0, s0[ll]); m1 = fmaxf(m1, s1[ll]); }
            float sum0 = 0.f, sum1 = 0.f;
            #pragma unroll
            for (int ll = 0; ll < L; ++ll) {
                s0[ll] = __expf(s0[ll] - m0); sum0 += s0[ll];
                s1[ll] = __expf(s1[ll] - m1); sum1 += s1[ll];
            }
            float inv0 = va0 ? 1.f / sum0 : 0.f;      // V already dis_r-scaled
            float inv1 = va1 ? 1.f / sum1 : 0.f;
            __half2 ha[4];
            #pragma unroll
            for (int i2 = 0; i2 < 4; ++i2) ha[i2] = __float2half2_rn(0.f);
            #pragma unroll
            for (int ll = 0; ll < L; ++ll) {
                __half2 p0 = __float2half2_rn(s0[ll] * inv0);
                __half2 p1 = __float2half2_rn(s1[ll] * inv1);
                #pragma unroll
                for (int i2 = 0; i2 < 4; ++i2) {
                    ha[i2] = __hfma2(p0, vv0[ll].hh[i2], ha[i2]);
                    ha[i2] = __hfma2(p1, vv1[ll].hh[i2], ha[i2]);
                }
            }
            #pragma unroll
            for (int i2 = 0; i2 < 4; ++i2) {
                float2 f = __half22float2(ha[i2]);
                acc[i2 * 2]     += f.x;
                acc[i2 * 2 + 1] += f.y;
            }
        }
        // ---- pair B: edges 2,3 ----
        {
            float s0[L], s1[L];
            #pragma unroll
            for (int ll = 0; ll < L; ++ll) {
                float p0 = 0.f, p1 = 0.f;
                #pragma unroll
                for (int i2 = 0; i2 < 4; ++i2) {
                    p0 = dot2(q.h[i2], kk2[ll].h[i2], p0);
                    p1 = dot2(q.h[i2], kk3[ll].h[i2], p1);
                }
                s0[ll] = p0 * 0.35355339059327373f;
                s1[ll] = p1 * 0.35355339059327373f;
            }
            float m0 = s0[0], m1 = s1[0];
            #pragma unroll
            for (int ll = 1; ll < L; ++ll) { m0 = fmaxf(m0, s0[ll]); m1 = fmaxf(m1, s1[ll]); }
            float sum0 = 0.f, sum1 = 0.f;
            #pragma unroll
            for (int ll = 0; ll < L; ++ll) {
                s0[ll] = __expf(s0[ll] - m0); sum0 += s0[ll];
                s1[ll] = __expf(s1[ll] - m1); sum1 += s1[ll];
            }
            float inv0 = va2 ? 1.f / sum0 : 0.f;
            float inv1 = va3 ? 1.f / sum1 : 0.f;
            __half2 ha[4];
            #pragma unroll
            for (int i2 = 0; i2 < 4; ++i2) ha[i2] = __float2half2_rn(0.f);
            #pragma unroll
            for (int ll = 0; ll < L; ++ll) {
                __half2 p0 = __float2half2_rn(s0[ll] * inv0);
                __half2 p1 = __float2half2_rn(s1[ll] * inv1);
                #pragma unroll
                for (int i2 = 0; i2 < 4; ++i2) {
                    ha[i2] = __hfma2(p0, vv2[ll].hh[i2], ha[i2]);
                    ha[i2] = __hfma2(p1, vv3[ll].hh[i2], ha[i2]);
                }
            }
            #pragma unroll
            for (int i2 = 0; i2 < 4; ++i2) {
                float2 f = __half22float2(ha[i2]);
                acc[i2 * 2]     += f.x;
                acc[i2 * 2 + 1] += f.y;
            }
        }
    }
    // reduce the 8 edge slots: every lane ends with the full sums for head u
    #pragma unroll
    for (int off = 8; off < 64; off <<= 1) {
        #pragma unroll
        for (int i = 0; i < 8; ++i) acc[i] += __shfl_xor(acc[i], off);
    }

    if constexpr (!FINAL) {
        if (slot == 0) {
            float4* dst = (float4*)(x_all + ((size_t)c * MAXL + L) * HID + u * 8);
            dst[0] = make_float4(fmaxf(acc[0] * nc, 0.f), fmaxf(acc[1] * nc, 0.f),
                                 fmaxf(acc[2] * nc, 0.f), fmaxf(acc[3] * nc, 0.f));
            dst[1] = make_float4(fmaxf(acc[4] * nc, 0.f), fmaxf(acc[5] * nc, 0.f),
                                 fmaxf(acc[6] * nc, 0.f), fmaxf(acc[7] * nc, 0.f));
        }
    } else {
        // fused classifier: logits = relu(slice3) @ W2 + b2, then log_softmax.
        float xn[8];
        #pragma unroll
        for (int i = 0; i < 8; ++i) xn[i] = fmaxf(acc[i] * nc, 0.f);
        float pl[4] = {0.f, 0.f, 0.f, 0.f};
        const float* w2p = w2 + (u * 8) * N_CLASS + slot * 4;
        #pragma unroll
        for (int i = 0; i < 8; ++i) {
            float4 wv4 = *(const float4*)(w2p + i * N_CLASS);
            pl[0] = fmaf(xn[i], wv4.x, pl[0]);
            pl[1] = fmaf(xn[i], wv4.y, pl[1]);
            pl[2] = fmaf(xn[i], wv4.z, pl[2]);
            pl[3] = fmaf(xn[i], wv4.w, pl[3]);
        }
        #pragma unroll
        for (int off = 1; off < 8; off <<= 1) {
            #pragma unroll
            for (int cc = 0; cc < 4; ++cc) pl[cc] += __shfl_xor(pl[cc], off);
        }
        float4 bb = *(const float4*)(b2 + slot * 4);
        pl[0] += bb.x; pl[1] += bb.y; pl[2] += bb.z; pl[3] += bb.w;
        float lm = fmaxf(fmaxf(pl[0], pl[1]), fmaxf(pl[2], pl[3]));
        #pragma unroll
        for (int off = 8; off < 64; off <<= 1) lm = fmaxf(lm, __shfl_xor(lm, off));
        float se = __expf(pl[0] - lm) + __expf(pl[1] - lm)
                 + __expf(pl[2] - lm) + __expf(pl[3] - lm);
        #pragma unroll
        for (int off = 8; off < 64; off <<= 1) se += __shfl_xor(se, off);
        float ls = logf(se);
        if (u == 0) {
            float4 o4 = make_float4(pl[0] - lm - ls, pl[1] - lm - ls,
                                    pl[2] - lm - ls, pl[3] - lm - ls);
            *(float4*)(out + (size_t)c * N_CLASS + slot * 4) = o4;
        }
    }
}

extern "C" void kernel_launch(void* const* d_in, const int* in_sizes, int n_in,
                              void* d_out, int out_size, void* d_ws, size_t ws_size,
                              hipStream_t stream) {
    const float* x      = (const float*)d_in[0];
    const int*   eidx   = (const int*)d_in[1];     // (2, E)
    const float* lin1_w = (const float*)d_in[2];
    const float* lin1_b = (const float*)d_in[3];
    const float* wq     = (const float*)d_in[4];   // (3, 8, 8, 8)
    const float* bq     = (const float*)d_in[5];   // (3, 64)
    const float* wk     = (const float*)d_in[6];
    const float* bk     = (const float*)d_in[7];
    const float* wv     = (const float*)d_in[8];
    const float* bv     = (const float*)d_in[9];
    const float* lin2_w = (const float*)d_in[10];  // (64, 32)
    const float* lin2_b = (const float*)d_in[11];
    float* out = (float*)d_out;

    const int n  = NN;
    const int E  = NE;
    const int* row = eidx;
    const int* col = eidx + E;

    // workspace layout (16B-aligned where vector-accessed)
    char* ws = (char*)d_ws;
    float*  x_all  = (float*)ws;   ws += (size_t)NN * MAXL * HID * 4;        // 25.6 MB
    f16x2*  Q2     = (f16x2*)ws;   ws += (size_t)NN * 32 * 4;                // 3.2 MB
    f16x2*  KV     = (f16x2*)ws;   ws += (size_t)NN * KVS * 2 * 32 * 4;      // 19.2 MB
    float*  dis    = (float*)ws;   ws += (size_t)NN * 4;
    int*    deg    = (int*)ws;     ws += (size_t)NN * 4;
    int*    rowptr = (int*)ws;     ws += (size_t)NN * 4;
    int*    cursor = (int*)ws;     ws += (size_t)NN * 4;
    int*    csr    = (int*)ws;     ws += (size_t)NE * 4;                     // 1.6 MB
    f16*    wt16   = (f16*)ws;     ws += (size_t)HID * F_IN * 2;             // 32 KB
    int*    bsum   = (int*)ws;     ws += 128 * 4;
    int*    dhist  = (int*)ws;     ws += 256 * 4;
    int*    bcur   = (int*)ws;     ws += 256 * 4;
    int*    perm   = (int*)ws;     ws += (size_t)NN * 4;

    const int degBlocks  = (E + 255) / 256;       // 1563
    const int lin1Blocks = (n + 63) / 64;         // 391
    const int t1Blocks   = (n * 32 + 255) / 256;  // 3125
    const int blocks     = (n + 3) / 4;           // gather: 4 nodes/block

    // 1. prep: wprep || zero deg || zero dhist
    prep_kernel<<<64 + SCAN_NB + 1, 256, 0, stream>>>(lin1_w, wt16, deg, dhist, n);

    // 2. deg histogram || lin1 MFMA (independent; one grid)
    deg_lin1_kernel<<<degBlocks + lin1Blocks, 256, 0, stream>>>(
        col, deg, E, degBlocks, x, (const f16x8*)wt16, lin1_b, x_all, n);

    // 3. scans: rowptr bases + degree-bucket histogram, then bucket scan, then scanC
    scanA_kernel<<<SCAN_NB, 256, 0, stream>>>(deg, bsum, dhist, n);
    bucketScan_kernel<<<1, 256, 0, stream>>>(dhist, bcur);
    scanC_kernel<<<SCAN_NB, 256, 0, stream>>>(deg, bsum, rowptr, cursor, dis, n);

    // 4. scatter CSR || layer-1 transform + degree-sorted perm (one grid)
    scatter_t1_kernel<<<degBlocks + t1Blocks, 256, 0, stream>>>(
        row, col, cursor, csr, E, degBlocks, x_all, wv, bv, dis, KV,
        deg, bcur, perm, n);

    // 5. layer-1 gather (softmax == identity)
    gather1_kernel<<<blocks, 256, 0, stream>>>(perm, rowptr, deg, csr, dis,
                                               (const f16x8*)KV, x_all, n);

    // 6. layer 2
    transform_kernel<<<t1Blocks, 256, 0, stream>>>(
        x_all, wq + 512, bq + 64, wk + 512, bk + 64, wv + 512, bv + 64,
        dis, Q2, KV, n, 2);
    gather_kernel<2, false><<<blocks, 256, 0, stream>>>(
        perm, rowptr, deg, csr, dis, (const f16x8*)Q2, (const f16x8*)KV,
        x_all, lin2_w, lin2_b, out, n);

    // 7. layer 3 with fused classifier + log_softmax
    transform_kernel<<<t1Blocks, 256, 0, stream>>>(
        x_all, wq + 1024, bq + 128, wk + 1024, bk + 128, wv + 1024, bv + 128,
        dis, Q2, KV, n, 3);
    gather_kernel<3, true><<<blocks, 256, 0, stream>>>(
        perm, rowptr, deg, csr, dis, (const f16x8*)Q2, (const f16x8*)KV,
        x_all, lin2_w, lin2_b, out, n);
}

// Round 14
// 272.528 us; speedup vs baseline: 1.4204x; 1.4204x over previous
//
#include <hip/hip_runtime.h>
#include <hip/hip_fp16.h>
#include <math.h>

#define NN 25000
#define NE 400000
#define HID 64
#define F_IN 256
#define N_CLASS 32
#define MAXL 4          // x_all stores up to 4 layer slices
#define KVS 3           // K/V layer slots
#define WPAD 264        // f16 row stride of W^T in LDS (256 + 8 pad -> 4-bank rotate)
#define SCAN_NB 98      // ceil(NN/256)

typedef _Float16 f16;
typedef _Float16 f16x2 __attribute__((ext_vector_type(2)));
typedef _Float16 f16x8 __attribute__((ext_vector_type(8)));
typedef float f32x4 __attribute__((ext_vector_type(4)));

union F16x8 {
    f16x8 v;
    f16x2 h[4];
    __half2 hh[4];
};

__device__ __forceinline__ float dot2(f16x2 a, f16x2 b, float c) {
#if __has_builtin(__builtin_amdgcn_fdot2)
    return __builtin_amdgcn_fdot2(a, b, c, false);
#else
    return c + (float)a[0] * (float)b[0] + (float)a[1] * (float)b[1];
#endif
}

// ---------- W1 -> fp16 transposed: wt[n][k] = (f16) w[k*64+n] ----------
__global__ void wprep_kernel(const float* __restrict__ w, f16* __restrict__ wt) {
    int e = blockIdx.x * blockDim.x + threadIdx.x;  // 16384 elements
    int k = e >> 6, nn = e & 63;
    wt[nn * F_IN + k] = (f16)w[e];
}

// ---------- fused: deg histogram (blocks < degBlocks)  ||  lin1 MFMA ----------
__global__ void __launch_bounds__(256) deg_lin1_kernel(
        const int* __restrict__ col, int* __restrict__ deg, int E, int degBlocks,
        const float* __restrict__ x, const f16x8* __restrict__ wt,
        const float* __restrict__ b, float* __restrict__ x_all, int n) {
    __shared__ f16 wlds[64 * WPAD];
    if (blockIdx.x < degBlocks) {
        int e = blockIdx.x * 256 + threadIdx.x;
        if (e < E) atomicAdd(&deg[col[e]], 1);
        return;
    }
    int bid = blockIdx.x - degBlocks;
    int t = threadIdx.x;
    #pragma unroll
    for (int j = 0; j < 8; ++j) {                 // stage all 2048 f16x8 units (32 KB)
        int idx = t + j * 256;
        int e = idx * 8;
        int nr = e >> 8, k0 = e & 255;
        *(f16x8*)&wlds[nr * WPAD + k0] = wt[idx];
    }
    __syncthreads();
    int wave = t >> 6, lane = t & 63;
    int m = lane & 15, quad = lane >> 4;
    int rowA = bid * 64 + wave * 16 + m;
    int rA = min(rowA, n - 1);                    // clamp; masked at store
    const float* xp = x + (size_t)rA * F_IN + quad * 8;
    f32x4 acc[4] = {};
    for (int kk = 0; kk < F_IN; kk += 32) {
        float4 x0 = *(const float4*)(xp + kk);
        float4 x1 = *(const float4*)(xp + kk + 4);
        f16x8 a;
        a[0] = (f16)x0.x; a[1] = (f16)x0.y; a[2] = (f16)x0.z; a[3] = (f16)x0.w;
        a[4] = (f16)x1.x; a[5] = (f16)x1.y; a[6] = (f16)x1.z; a[7] = (f16)x1.w;
        #pragma unroll
        for (int nt = 0; nt < 4; ++nt) {
            f16x8 bf = *(const f16x8*)&wlds[(nt * 16 + m) * WPAD + kk + quad * 8];
            acc[nt] = __builtin_amdgcn_mfma_f32_16x16x32_f16(a, bf, acc[nt], 0, 0, 0);
        }
    }
    int rowC = bid * 64 + wave * 16 + quad * 4;
    #pragma unroll
    for (int nt = 0; nt < 4; ++nt) {
        int c2 = nt * 16 + m;
        float bias = b[c2];
        #pragma unroll
        for (int r = 0; r < 4; ++r) {
            int row = rowC + r;
            if (row < n)
                x_all[(size_t)row * (MAXL * HID) + c2] = fmaxf(acc[nt][r] + bias, 0.f);
        }
    }
}

// ---------- device-wide exclusive scan, 2 phases ----------
__global__ void scanA_kernel(const int* __restrict__ deg, int* __restrict__ bsum, int n) {
    int t = threadIdx.x;
    int i = blockIdx.x * 256 + t;
    int v = (i < n) ? deg[i] : 0;
    #pragma unroll
    for (int off = 1; off < 64; off <<= 1) v += __shfl_xor(v, off);
    __shared__ int wsum[4];
    if ((t & 63) == 0) wsum[t >> 6] = v;
    __syncthreads();
    if (t == 0) bsum[blockIdx.x] = wsum[0] + wsum[1] + wsum[2] + wsum[3];
}

// scanC: each block re-scans the (<=128) block sums in LDS, then local scan
__global__ void scanC_kernel(const int* __restrict__ deg, const int* __restrict__ bsum,
                             int* __restrict__ rowptr, int* __restrict__ cursor,
                             float* __restrict__ dis, int n) {
    __shared__ int s[128];
    int t = threadIdx.x;
    {   // inclusive HS scan of block sums
        int v = (t < SCAN_NB) ? bsum[t] : 0;
        s[t] = v;
        __syncthreads();
        for (int off = 1; off < 128; off <<= 1) {
            int u = (t >= off) ? s[t - off] : 0;
            __syncthreads();
            s[t] += u;
            __syncthreads();
        }
    }
    int base = (blockIdx.x > 0) ? s[blockIdx.x - 1] : 0;   // exclusive base of this block
    __syncthreads();

    int i = blockIdx.x * 256 + t;
    int lane = t & 63, w = t >> 6;
    int v = (i < n) ? deg[i] : 0;
    int x = v;   // inclusive wave scan
    #pragma unroll
    for (int off = 1; off < 64; off <<= 1) {
        int u = __shfl_up(x, off);
        if (lane >= off) x += u;
    }
    __shared__ int wsum[4];
    if (lane == 63) wsum[w] = x;
    __syncthreads();
    for (int ww = 0; ww < w; ++ww) base += wsum[ww];
    if (i < n) {
        int excl = base + x - v;
        rowptr[i] = excl;
        cursor[i] = excl;
        dis[i] = rsqrtf((float)(v + 1));   // +1 self loop
    }
}

// ---------- fused: scatter edges into CSR  ||  layer-1 transform (V only) ----------
__global__ void scatter_t1_kernel(const int* __restrict__ row, const int* __restrict__ col,
                                  int* __restrict__ cursor, int* __restrict__ csr_src,
                                  int E, int scatBlocks,
                                  const float* __restrict__ x_all,
                                  const float* __restrict__ wv, const float* __restrict__ bv,
                                  const float* __restrict__ dis,
                                  f16x2* __restrict__ KV, int n) {
    if (blockIdx.x < scatBlocks) {
        int e = blockIdx.x * 256 + threadIdx.x;
        if (e >= E) return;
        int c = col[e];
        int p = atomicAdd(&cursor[c], 1);
        csr_src[p] = row[e];
        return;
    }
    int t = (blockIdx.x - scatBlocks) * 256 + threadIdx.x;
    int node = t >> 5, u = t & 31;
    if (node >= n) return;
    int g = u >> 2;
    int o0 = (u & 3) * 2;
    const float4* xg4 = (const float4*)(x_all + (size_t)node * (MAXL * HID) + g * 8);
    float4 xa = xg4[0], xb = xg4[1];
    float xv[8] = {xa.x, xa.y, xa.z, xa.w, xb.x, xb.y, xb.z, xb.w};
    float d = dis[node];
    const float* wgv = wv + g * 64;
    float v0 = bv[g * 8 + o0], v1 = bv[g * 8 + o0 + 1];
    #pragma unroll
    for (int i = 0; i < 8; ++i) {
        v0 = fmaf(xv[i], wgv[i * 8 + o0], v0);
        v1 = fmaf(xv[i], wgv[i * 8 + o0 + 1], v1);
    }
    f16x2 vh; vh[0] = (f16)(v0 * d); vh[1] = (f16)(v1 * d);
    KV[((size_t)node * KVS * 2 + 1) * 32 + u] = vh;   // slice 0, V slot
}

// ---------- layer-1 gather: pure weighted V sum (softmax == 1) ----------
__global__ void gather1_kernel(const int* __restrict__ rowptr, const int* __restrict__ deg,
                               const int* __restrict__ csr_src, const float* __restrict__ dis,
                               const f16x8* __restrict__ KV8, float* __restrict__ x_all, int n) {
    int wave = (int)((blockIdx.x * (size_t)blockDim.x + threadIdx.x) >> 6);
    int lane = threadIdx.x & 63;
    if (wave >= n) return;
    int c = wave;
    int u = lane & 7;
    int slot = lane >> 3;
    float nc = dis[c];
    int beg = rowptr[c];
    int dc = deg[c] + 1;      // + self loop (virtual edge 0)
    float acc[8];
    #pragma unroll
    for (int i = 0; i < 8; ++i) acc[i] = 0.f;

    for (int j = 0; j < dc; j += 32) {
        int jj0 = j + slot, jj1 = jj0 + 8, jj2 = jj0 + 16, jj3 = jj0 + 24;
        bool va0 = jj0 < dc, va1 = jj1 < dc, va2 = jj2 < dc, va3 = jj3 < dc;
        int r0 = c, r1 = c, r2 = c, r3 = c;
        if (va0 && jj0 > 0) r0 = csr_src[beg + jj0 - 1];
        if (va1)            r1 = csr_src[beg + jj1 - 1];
        if (va2)            r2 = csr_src[beg + jj2 - 1];
        if (va3)            r3 = csr_src[beg + jj3 - 1];
        F16x8 v0, v1, v2, v3;
        v0.v = KV8[(size_t)r0 * (KVS * 2 * 8) + 8 + u];
        v1.v = KV8[(size_t)r1 * (KVS * 2 * 8) + 8 + u];
        v2.v = KV8[(size_t)r2 * (KVS * 2 * 8) + 8 + u];
        v3.v = KV8[(size_t)r3 * (KVS * 2 * 8) + 8 + u];
        __half2 p0 = __float2half2_rn(va0 ? 1.f : 0.f);
        __half2 p1 = __float2half2_rn(va1 ? 1.f : 0.f);
        __half2 p2 = __float2half2_rn(va2 ? 1.f : 0.f);
        __half2 p3 = __float2half2_rn(va3 ? 1.f : 0.f);
        __half2 ha[4];
        #pragma unroll
        for (int i2 = 0; i2 < 4; ++i2) {
            ha[i2] = __hmul2(p0, v0.hh[i2]);
            ha[i2] = __hfma2(p1, v1.hh[i2], ha[i2]);
            ha[i2] = __hfma2(p2, v2.hh[i2], ha[i2]);
            ha[i2] = __hfma2(p3, v3.hh[i2], ha[i2]);
        }
        #pragma unroll
        for (int i2 = 0; i2 < 4; ++i2) {
            float2 f = __half22float2(ha[i2]);
            acc[i2 * 2]     += f.x;
            acc[i2 * 2 + 1] += f.y;
        }
    }
    #pragma unroll
    for (int off = 8; off < 64; off <<= 1) {
        #pragma unroll
        for (int i = 0; i < 8; ++i) acc[i] += __shfl_xor(acc[i], off);
    }
    if (slot == 0) {
        float4* dst = (float4*)(x_all + ((size_t)c * MAXL + 1) * HID + u * 8);
        dst[0] = make_float4(fmaxf(acc[0] * nc, 0.f), fmaxf(acc[1] * nc, 0.f),
                             fmaxf(acc[2] * nc, 0.f), fmaxf(acc[3] * nc, 0.f));
        dst[1] = make_float4(fmaxf(acc[4] * nc, 0.f), fmaxf(acc[5] * nc, 0.f),
                             fmaxf(acc[6] * nc, 0.f), fmaxf(acc[7] * nc, 0.f));
    }
}

// ---------- per-node q/k/v grouped-linear transform (layers 2,3) ----------
// V is pre-scaled by dis[node]
__global__ void transform_kernel(const float* __restrict__ x_all,
                                 const float* __restrict__ wq, const float* __restrict__ bq,
                                 const float* __restrict__ wk, const float* __restrict__ bk,
                                 const float* __restrict__ wv, const float* __restrict__ bv,
                                 const float* __restrict__ dis,
                                 f16x2* __restrict__ Q2, f16x2* __restrict__ KV,
                                 int n, int L) {
    int t = blockIdx.x * blockDim.x + threadIdx.x;
    int node = t >> 5, u = t & 31;
    if (node >= n) return;
    int g = u >> 2;               // head/group of both dims
    int o0 = (u & 3) * 2;         // within-group output index of dim 2u
    const float* xrow = x_all + (size_t)node * (MAXL * HID);
    float d = dis[node];

    {   // Q from layer L-1
        const float4* xg4 = (const float4*)(xrow + (L - 1) * HID + g * 8);
        float4 xa = xg4[0], xb = xg4[1];
        float xv[8] = {xa.x, xa.y, xa.z, xa.w, xb.x, xb.y, xb.z, xb.w};
        const float* wg = wq + g * 64;
        float a0 = bq[g * 8 + o0], a1 = bq[g * 8 + o0 + 1];
        #pragma unroll
        for (int i = 0; i < 8; ++i) {
            a0 = fmaf(xv[i], wg[i * 8 + o0], a0);
            a1 = fmaf(xv[i], wg[i * 8 + o0 + 1], a1);
        }
        f16x2 q; q[0] = (f16)a0; q[1] = (f16)a1;
        Q2[(size_t)node * 32 + u] = q;
    }
    for (int ll = 0; ll < L; ++ll) {
        const float4* xg4 = (const float4*)(xrow + ll * HID + g * 8);
        float4 xa = xg4[0], xb = xg4[1];
        float xv[8] = {xa.x, xa.y, xa.z, xa.w, xb.x, xb.y, xb.z, xb.w};
        const float* wgk = wk + g * 64;
        const float* wgv = wv + g * 64;
        float k0 = bk[g * 8 + o0], k1 = bk[g * 8 + o0 + 1];
        float v0 = bv[g * 8 + o0], v1 = bv[g * 8 + o0 + 1];
        #pragma unroll
        for (int i = 0; i < 8; ++i) {
            k0 = fmaf(xv[i], wgk[i * 8 + o0], k0);
            k1 = fmaf(xv[i], wgk[i * 8 + o0 + 1], k1);
            v0 = fmaf(xv[i], wgv[i * 8 + o0], v0);
            v1 = fmaf(xv[i], wgv[i * 8 + o0 + 1], v1);
        }
        f16x2 kh; kh[0] = (f16)k0; kh[1] = (f16)k1;
        f16x2 vh; vh[0] = (f16)(v0 * d); vh[1] = (f16)(v1 * d);   // dis-scaled V
        size_t base = ((size_t)node * KVS + ll) * 2;
        KV[(base + 0) * 32 + u] = kh;
        KV[(base + 1) * 32 + u] = vh;
    }
}

// ---------- gather + attend core (layers 2,3): 32 edges/iter, straight-line ----------
// FINAL=true (L=3): fused classifier + log_softmax, writes `out`, skips x_all store.
template <int L, bool FINAL>
__global__ void gather_kernel(const int* __restrict__ rowptr, const int* __restrict__ deg,
                              const int* __restrict__ csr_src, const float* __restrict__ dis,
                              const f16x8* __restrict__ Q8, const f16x8* __restrict__ KV8,
                              float* __restrict__ x_all,
                              const float* __restrict__ w2, const float* __restrict__ b2,
                              float* __restrict__ out, int n) {
    int wave = (int)((blockIdx.x * (size_t)blockDim.x + threadIdx.x) >> 6);
    int lane = threadIdx.x & 63;
    if (wave >= n) return;
    int c = wave;
    int u = lane & 7;         // head
    int slot = lane >> 3;     // edge slot
    F16x8 q; q.v = Q8[(size_t)c * 8 + u];
    float nc = dis[c];
    int beg = rowptr[c];
    int dc = deg[c] + 1;      // + self loop (virtual edge 0)
    float acc[8];
    #pragma unroll
    for (int i = 0; i < 8; ++i) acc[i] = 0.f;

    for (int j = 0; j < dc; j += 32) {
        int jj0 = j + slot;
        int jj1 = jj0 + 8;
        int jj2 = jj0 + 16;
        int jj3 = jj0 + 24;
        bool va0 = jj0 < dc, va1 = jj1 < dc, va2 = jj2 < dc, va3 = jj3 < dc;
        int r0 = c, r1 = c, r2 = c, r3 = c;
        if (va0 && jj0 > 0) r0 = csr_src[beg + jj0 - 1];
        if (va1)            r1 = csr_src[beg + jj1 - 1];
        if (va2)            r2 = csr_src[beg + jj2 - 1];
        if (va3)            r3 = csr_src[beg + jj3 - 1];

        size_t rb0 = (size_t)r0 * (KVS * 2 * 8);
        size_t rb1 = (size_t)r1 * (KVS * 2 * 8);
        size_t rb2 = (size_t)r2 * (KVS * 2 * 8);
        size_t rb3 = (size_t)r3 * (KVS * 2 * 8);
        F16x8 kk0[L], vv0[L], kk1[L], vv1[L], kk2[L], vv2[L], kk3[L], vv3[L];
        #pragma unroll
        for (int ll = 0; ll < L; ++ll) {
            kk0[ll].v = KV8[rb0 + ll * 16 + u];
            vv0[ll].v = KV8[rb0 + ll * 16 + 8 + u];
            kk1[ll].v = KV8[rb1 + ll * 16 + u];
            vv1[ll].v = KV8[rb1 + ll * 16 + 8 + u];
            kk2[ll].v = KV8[rb2 + ll * 16 + u];
            vv2[ll].v = KV8[rb2 + ll * 16 + 8 + u];
            kk3[ll].v = KV8[rb3 + ll * 16 + u];
            vv3[ll].v = KV8[rb3 + ll * 16 + 8 + u];
        }

        // ---- pair A: edges 0,1 ----
        {
            float s0[L], s1[L];
            #pragma unroll
            for (int ll = 0; ll < L; ++ll) {
                float p0 = 0.f, p1 = 0.f;
                #pragma unroll
                for (int i2 = 0; i2 < 4; ++i2) {
                    p0 = dot2(q.h[i2], kk0[ll].h[i2], p0);
                    p1 = dot2(q.h[i2], kk1[ll].h[i2], p1);
                }
                s0[ll] = p0 * 0.35355339059327373f;   // 1/sqrt(8)
                s1[ll] = p1 * 0.35355339059327373f;
            }
            float m0 = s0[0], m1 = s1[0];
            #pragma unroll
            for (int ll = 1; ll < L; ++ll) { m0 = fmaxf(m0, s0[ll]); m1 = fmaxf(m1, s1[ll]); }
            float sum0 = 0.f, sum1 = 0.f;
            #pragma unroll
            for (int ll = 0; ll < L; ++ll) {
                s0[ll] = __expf(s0[ll] - m0); sum0 += s0[ll];
                s1[ll] = __expf(s1[ll] - m1); sum1 += s1[ll];
            }
            float inv0 = va0 ? 1.f / sum0 : 0.f;      // V already dis_r-scaled
            float inv1 = va1 ? 1.f / sum1 : 0.f;
            __half2 ha[4];
            #pragma unroll
            for (int i2 = 0; i2 < 4; ++i2) ha[i2] = __float2half2_rn(0.f);
            #pragma unroll
            for (int ll = 0; ll < L; ++ll) {
                __half2 p0 = __float2half2_rn(s0[ll] * inv0);
                __half2 p1 = __float2half2_rn(s1[ll] * inv1);
                #pragma unroll
                for (int i2 = 0; i2 < 4; ++i2) {
                    ha[i2] = __hfma2(p0, vv0[ll].hh[i2], ha[i2]);
                    ha[i2] = __hfma2(p1, vv1[ll].hh[i2], ha[i2]);
                }
            }
            #pragma unroll
            for (int i2 = 0; i2 < 4; ++i2) {
                float2 f = __half22float2(ha[i2]);
                acc[i2 * 2]     += f.x;
                acc[i2 * 2 + 1] += f.y;
            }
        }
        // ---- pair B: edges 2,3 ----
        {
            float s0[L], s1[L];
            #pragma unroll
            for (int ll = 0; ll < L; ++ll) {
                float p0 = 0.f, p1 = 0.f;
                #pragma unroll
                for (int i2 = 0; i2 < 4; ++i2) {
                    p0 = dot2(q.h[i2], kk2[ll].h[i2], p0);
                    p1 = dot2(q.h[i2], kk3[ll].h[i2], p1);
                }
                s0[ll] = p0 * 0.35355339059327373f;
                s1[ll] = p1 * 0.35355339059327373f;
            }
            float m0 = s0[0], m1 = s1[0];
            #pragma unroll
            for (int ll = 1; ll < L; ++ll) { m0 = fmaxf(m0, s0[ll]); m1 = fmaxf(m1, s1[ll]); }
            float sum0 = 0.f, sum1 = 0.f;
            #pragma unroll
            for (int ll = 0; ll < L; ++ll) {
                s0[ll] = __expf(s0[ll] - m0); sum0 += s0[ll];
                s1[ll] = __expf(s1[ll] - m1); sum1 += s1[ll];
            }
            float inv0 = va2 ? 1.f / sum0 : 0.f;
            float inv1 = va3 ? 1.f / sum1 : 0.f;
            __half2 ha[4];
            #pragma unroll
            for (int i2 = 0; i2 < 4; ++i2) ha[i2] = __float2half2_rn(0.f);
            #pragma unroll
            for (int ll = 0; ll < L; ++ll) {
                __half2 p0 = __float2half2_rn(s0[ll] * inv0);
                __half2 p1 = __float2half2_rn(s1[ll] * inv1);
                #pragma unroll
                for (int i2 = 0; i2 < 4; ++i2) {
                    ha[i2] = __hfma2(p0, vv2[ll].hh[i2], ha[i2]);
                    ha[i2] = __hfma2(p1, vv3[ll].hh[i2], ha[i2]);
                }
            }
            #pragma unroll
            for (int i2 = 0; i2 < 4; ++i2) {
                float2 f = __half22float2(ha[i2]);
                acc[i2 * 2]     += f.x;
                acc[i2 * 2 + 1] += f.y;
            }
        }
    }
    // reduce the 8 edge slots: every lane ends with the full sums for head u
    #pragma unroll
    for (int off = 8; off < 64; off <<= 1) {
        #pragma unroll
        for (int i = 0; i < 8; ++i) acc[i] += __shfl_xor(acc[i], off);
    }

    if constexpr (!FINAL) {
        if (slot == 0) {
            float4* dst = (float4*)(x_all + ((size_t)c * MAXL + L) * HID + u * 8);
            dst[0] = make_float4(fmaxf(acc[0] * nc, 0.f), fmaxf(acc[1] * nc, 0.f),
                                 fmaxf(acc[2] * nc, 0.f), fmaxf(acc[3] * nc, 0.f));
            dst[1] = make_float4(fmaxf(acc[4] * nc, 0.f), fmaxf(acc[5] * nc, 0.f),
                                 fmaxf(acc[6] * nc, 0.f), fmaxf(acc[7] * nc, 0.f));
        }
    } else {
        // fused classifier: logits = relu(slice3) @ W2 + b2, then log_softmax.
        // lane (slot,u) computes partial logits for classes slot*4..slot*4+3
        // over dims u*8..u*8+7, reduced over u by xor{1,2,4}.
        float xn[8];
        #pragma unroll
        for (int i = 0; i < 8; ++i) xn[i] = fmaxf(acc[i] * nc, 0.f);
        float pl[4] = {0.f, 0.f, 0.f, 0.f};
        const float* w2p = w2 + (u * 8) * N_CLASS + slot * 4;
        #pragma unroll
        for (int i = 0; i < 8; ++i) {
            float4 wv4 = *(const float4*)(w2p + i * N_CLASS);
            pl[0] = fmaf(xn[i], wv4.x, pl[0]);
            pl[1] = fmaf(xn[i], wv4.y, pl[1]);
            pl[2] = fmaf(xn[i], wv4.z, pl[2]);
            pl[3] = fmaf(xn[i], wv4.w, pl[3]);
        }
        #pragma unroll
        for (int off = 1; off < 8; off <<= 1) {
            #pragma unroll
            for (int cc = 0; cc < 4; ++cc) pl[cc] += __shfl_xor(pl[cc], off);
        }
        float4 bb = *(const float4*)(b2 + slot * 4);
        pl[0] += bb.x; pl[1] += bb.y; pl[2] += bb.z; pl[3] += bb.w;
        float lm = fmaxf(fmaxf(pl[0], pl[1]), fmaxf(pl[2], pl[3]));
        #pragma unroll
        for (int off = 8; off < 64; off <<= 1) lm = fmaxf(lm, __shfl_xor(lm, off));
        float se = __expf(pl[0] - lm) + __expf(pl[1] - lm)
                 + __expf(pl[2] - lm) + __expf(pl[3] - lm);
        #pragma unroll
        for (int off = 8; off < 64; off <<= 1) se += __shfl_xor(se, off);
        float ls = logf(se);
        if (u == 0) {
            float4 o4 = make_float4(pl[0] - lm - ls, pl[1] - lm - ls,
                                    pl[2] - lm - ls, pl[3] - lm - ls);
            *(float4*)(out + (size_t)c * N_CLASS + slot * 4) = o4;
        }
    }
}

extern "C" void kernel_launch(void* const* d_in, const int* in_sizes, int n_in,
                              void* d_out, int out_size, void* d_ws, size_t ws_size,
                              hipStream_t stream) {
    const float* x      = (const float*)d_in[0];
    const int*   eidx   = (const int*)d_in[1];     // (2, E)
    const float* lin1_w = (const float*)d_in[2];
    const float* lin1_b = (const float*)d_in[3];
    const float* wq     = (const float*)d_in[4];   // (3, 8, 8, 8)
    const float* bq     = (const float*)d_in[5];   // (3, 64)
    const float* wk     = (const float*)d_in[6];
    const float* bk     = (const float*)d_in[7];
    const float* wv     = (const float*)d_in[8];
    const float* bv     = (const float*)d_in[9];
    const float* lin2_w = (const float*)d_in[10];  // (64, 32)
    const float* lin2_b = (const float*)d_in[11];
    float* out = (float*)d_out;

    const int n  = NN;
    const int E  = NE;
    const int* row = eidx;
    const int* col = eidx + E;

    // workspace layout (16B-aligned where vector-accessed)
    char* ws = (char*)d_ws;
    float*  x_all  = (float*)ws;   ws += (size_t)NN * MAXL * HID * 4;        // 25.6 MB
    f16x2*  Q2     = (f16x2*)ws;   ws += (size_t)NN * 32 * 4;                // 3.2 MB
    f16x2*  KV     = (f16x2*)ws;   ws += (size_t)NN * KVS * 2 * 32 * 4;      // 19.2 MB
    float*  dis    = (float*)ws;   ws += (size_t)NN * 4;
    int*    deg    = (int*)ws;     ws += (size_t)NN * 4;
    int*    rowptr = (int*)ws;     ws += (size_t)NN * 4;
    int*    cursor = (int*)ws;     ws += (size_t)NN * 4;
    int*    csr    = (int*)ws;     ws += (size_t)NE * 4;                     // 1.6 MB
    f16*    wt16   = (f16*)ws;     ws += (size_t)HID * F_IN * 2;             // 32 KB
    int*    bsum   = (int*)ws;     ws += 128 * 4;

    const int degBlocks  = (E + 255) / 256;       // 1563
    const int lin1Blocks = (n + 63) / 64;         // 391
    const int t1Blocks   = (n * 32 + 255) / 256;  // 3125
    const int blocks     = (n + 3) / 4;           // gather: 4 nodes/block

    // 1. prep: zero deg, W1 fp16 transpose
    hipMemsetAsync(deg, 0, (size_t)NN * 4, stream);
    wprep_kernel<<<(HID * F_IN + 255) / 256, 256, 0, stream>>>(lin1_w, wt16);

    // 2. deg histogram || lin1 MFMA (independent; one grid)
    deg_lin1_kernel<<<degBlocks + lin1Blocks, 256, 0, stream>>>(
        col, deg, E, degBlocks, x, (const f16x8*)wt16, lin1_b, x_all, n);

    // 3. scan -> rowptr/cursor/dis
    scanA_kernel<<<SCAN_NB, 256, 0, stream>>>(deg, bsum, n);
    scanC_kernel<<<SCAN_NB, 256, 0, stream>>>(deg, bsum, rowptr, cursor, dis, n);

    // 4. scatter CSR || layer-1 transform (independent; one grid)
    scatter_t1_kernel<<<degBlocks + t1Blocks, 256, 0, stream>>>(
        row, col, cursor, csr, E, degBlocks, x_all, wv, bv, dis, KV, n);

    // 5. layer-1 gather (softmax == identity)
    gather1_kernel<<<blocks, 256, 0, stream>>>(rowptr, deg, csr, dis,
                                               (const f16x8*)KV, x_all, n);

    // 6. layer 2
    transform_kernel<<<t1Blocks, 256, 0, stream>>>(
        x_all, wq + 512, bq + 64, wk + 512, bk + 64, wv + 512, bv + 64,
        dis, Q2, KV, n, 2);
    gather_kernel<2, false><<<blocks, 256, 0, stream>>>(
        rowptr, deg, csr, dis, (const f16x8*)Q2, (const f16x8*)KV,
        x_all, lin2_w, lin2_b, out, n);

    // 7. layer 3 with fused classifier + log_softmax
    transform_kernel<<<t1Blocks, 256, 0, stream>>>(
        x_all, wq + 1024, bq + 128, wk + 1024, bk + 128, wv + 1024, bv + 128,
        dis, Q2, KV, n, 3);
    gather_kernel<3, true><<<blocks, 256, 0, stream>>>(
        rowptr, deg, csr, dis, (const f16x8*)Q2, (const f16x8*)KV,
        x_all, lin2_w, lin2_b, out, n);
}